// Round 7
// baseline (575.886 us; speedup 1.0000x reference)
//
#include <hip/hip_runtime.h>
#include <hip/hip_bf16.h>

typedef __attribute__((ext_vector_type(8))) short short8;
typedef __attribute__((ext_vector_type(4))) float f32x4;

#define NB 8
#define NS 1024
#define NH 12
#define ND 64
#define NHID 768
#define N3 2304

#define SBAR() __builtin_amdgcn_sched_barrier(0)

__device__ __forceinline__ unsigned short f2bf(float f) {
  __hip_bfloat16 h = __float2bfloat16(f);
  return *reinterpret_cast<unsigned short*>(&h);
}
__device__ __forceinline__ float bf2f(unsigned short u) {
  __hip_bfloat16 h;
  *reinterpret_cast<unsigned short*>(&h) = u;
  return __bfloat162float(h);
}

// ---- cast hidden f32 -> bf16 ----
__global__ void k_cast(const float* __restrict__ in, unsigned short* __restrict__ out, int n4) {
  int i = blockIdx.x * blockDim.x + threadIdx.x;
  if (i >= n4) return;
  float4 v = ((const float4*)in)[i];
  ushort4 o;
  o.x = f2bf(v.x); o.y = f2bf(v.y); o.z = f2bf(v.z); o.w = f2bf(v.w);
  ((ushort4*)out)[i] = o;
}

// ---- pack mask [B][S] int -> bitmask [B][16] u64 ----
__global__ void k_mask(const int* __restrict__ mask, unsigned long long* __restrict__ bits) {
  int b = blockIdx.x, t = threadIdx.x;
  unsigned long long bal = __ballot(mask[b * NS + t] != 0);
  if ((t & 63) == 0) bits[b * 16 + (t >> 6)] = bal;
}

// ---- transpose-cast W [768][2304] f32 -> Wt [2304][768] bf16 ----
__global__ __launch_bounds__(256) void k_wt(const float* __restrict__ W, unsigned short* __restrict__ Wt) {
  __shared__ float tile[32][33];
  int r0 = blockIdx.x * 32;   // over 768
  int c0 = blockIdx.y * 32;   // over 2304
  int tx = threadIdx.x & 31, ty = threadIdx.x >> 5;
#pragma unroll
  for (int p = 0; p < 4; ++p)
    tile[ty + 8*p][tx] = W[(size_t)(r0 + ty + 8*p) * N3 + c0 + tx];
  __syncthreads();
#pragma unroll
  for (int p = 0; p < 4; ++p)
    Wt[(size_t)(c0 + ty + 8*p) * NHID + r0 + tx] = f2bf(tile[tx][ty + 8*p]);
}

// ---- QKV GEMM: [8192][768]bf16 @ Wt[2304][768]bf16 -> qkv [8192][2304]bf16 ----
__global__ __launch_bounds__(256) void k_qkv(const unsigned short* __restrict__ A,
                                             const unsigned short* __restrict__ Wt,
                                             const float* __restrict__ qb,
                                             const float* __restrict__ vb,
                                             unsigned short* __restrict__ out) {
  const int t = threadIdx.x;
  const int w = t >> 6, l = t & 63, l15 = l & 15, lhi = l >> 4;
  const int rowbase = blockIdx.x * 128 + w * 32;
  const int colbase = blockIdx.y * 64;

  f32x4 acc[2][4] = {};
  const unsigned short* arow0 = A + (size_t)(rowbase + l15) * NHID;
  const unsigned short* arow1 = A + (size_t)(rowbase + 16 + l15) * NHID;
  const unsigned short* wrows[4];
#pragma unroll
  for (int n = 0; n < 4; ++n)
    wrows[n] = Wt + (size_t)(colbase + n * 16 + l15) * NHID;

  for (int k0 = 0; k0 < NHID; k0 += 32) {
    short8 a0 = *(const short8*)(arow0 + k0 + lhi * 8);
    short8 a1 = *(const short8*)(arow1 + k0 + lhi * 8);
#pragma unroll
    for (int n = 0; n < 4; ++n) {
      short8 bfr = *(const short8*)(wrows[n] + k0 + lhi * 8);
      acc[0][n] = __builtin_amdgcn_mfma_f32_16x16x32_bf16(a0, bfr, acc[0][n], 0, 0, 0);
      acc[1][n] = __builtin_amdgcn_mfma_f32_16x16x32_bf16(a1, bfr, acc[1][n], 0, 0, 0);
    }
  }
  const int seg = colbase / NHID;   // uniform per block: 0=q 1=k 2=v
#pragma unroll
  for (int n = 0; n < 4; ++n) {
    int col = colbase + n * 16 + l15;
    int cc = col % NHID;
    float bias = (seg == 0) ? qb[cc] : (seg == 2) ? vb[cc] : 0.0f;
#pragma unroll
    for (int m = 0; m < 2; ++m) {
#pragma unroll
      for (int r = 0; r < 4; ++r) {
        int row = rowbase + m * 16 + lhi * 4 + r;
        float v = acc[m][n][r];
        if (seg == 0) v = (v + bias) * 0.125f;
        else if (seg == 2) v = v + bias;
        out[(size_t)row * N3 + col] = f2bf(v);
      }
    }
  }
}

// ---- transpose V (cols 1536..2303 of qkv) -> Vt [96][64][1024] bf16 ----
__global__ __launch_bounds__(256) void k_vt(const unsigned short* __restrict__ qkvb,
                                            unsigned short* __restrict__ Vt) {
  __shared__ unsigned short tile[32][33];
  int s0 = blockIdx.x * 32;  // over 1024
  int d0 = blockIdx.y * 32;  // over 64
  int bh = blockIdx.z;       // 0..95
  int b = bh / NH;
  int hcol = (bh % NH) * ND;
  int tx = threadIdx.x & 31, ty = threadIdx.x >> 5;
#pragma unroll
  for (int p = 0; p < 4; ++p) {
    int s = s0 + ty + 8*p;
    tile[ty + 8*p][tx] = qkvb[(size_t)(b * NS + s) * N3 + 2 * NHID + hcol + d0 + tx];
  }
  __syncthreads();
#pragma unroll
  for (int p = 0; p < 4; ++p) {
    int d = d0 + ty + 8*p;
    Vt[((size_t)bh * ND + d) * NS + s0 + tx] = tile[tx][ty + 8*p];
  }
}

// ---- fused attention: one block per (qtile16, h, b), 4 waves x 256 keys ----
// Fully-fused streaming loop: per c-iter do K+rel+rel2 loads (1 ahead),
// QK MFMA, exp, pack; every odd c: stage 32-key window through a tiny
// per-wave LDS buffer and run 4 PV MFMAs with V loaded in-loop. No big
// p_lds, no mid-kernel barrier; packed p kept in 32 VGPRs for probs out.
__global__ __launch_bounds__(256, 4) void k_attn(const unsigned short* __restrict__ qkvb,
                                                 const unsigned short* __restrict__ Vt,
                                                 const float* __restrict__ relp,
                                                 const float* __restrict__ rel2,
                                                 const unsigned long long* __restrict__ mbits,
                                                 float* __restrict__ outp) {
  __shared__ __align__(16) unsigned short stage[4][16][40];  // per-wave window stage, 5 KB
  __shared__ float ctx_lds[4][16][64];                       // 16 KB
  __shared__ float rs_lds[4][16];
  __shared__ float inv_lds[16];

  const int qt = blockIdx.x, h = blockIdx.y, b = blockIdx.z;
  const int t = threadIdx.x, w = t >> 6, l = t & 63, l15 = l & 15, lhi = l >> 4;
  const int bh = b * NH + h;
  const int wk = w * 256;                       // this wave's key base

  // Q fragments (16 rows x 64 d); q already scaled+biased in k_qkv
  const unsigned short* qrowp = qkvb + (size_t)(b * NS + qt * 16 + l15) * N3 + h * ND;
  short8 qa0 = *(const short8*)(qrowp + lhi * 8);
  short8 qa1 = *(const short8*)(qrowp + 32 + lhi * 8);

  const float* relrow  = relp + ((size_t)bh * NS + qt * 16 + l15) * NS;
  const float* rel2row = rel2 + ((size_t)bh * NS + qt * 16 + l15) * NS;
  const unsigned long long* mwp = mbits + b * 16 + w * 4;
  unsigned long long mw[4];
#pragma unroll
  for (int i = 0; i < 4; ++i) mw[i] = mwp[i];

  const unsigned short* kbase = qkvb + (size_t)(b * NS + l15) * N3 + NHID + h * ND;
  const unsigned short* vtb = Vt + (size_t)bh * ND * NS;

  // rolling 1-c-iter-ahead prefetch regs
  short8 k0s[2], k1s[2];
  float4 Ra[2], Rb[2];
  {
    const unsigned short* kr = kbase + (size_t)wk * N3;
    k0s[0] = *(const short8*)(kr + lhi * 8);
    k1s[0] = *(const short8*)(kr + 32 + lhi * 8);
    Ra[0] = *(const float4*)(relrow + wk + lhi * 4);
    Rb[0] = *(const float4*)(rel2row + wk + lhi * 4);
  }

  unsigned int pk[16][2];       // packed bf16 p, statically indexed (full unroll)
  f32x4 cacc[4] = {};           // ctx partials: 16 q-rows x 64 d for this wave's keys
  short8 vf[4];
  float rs = 0.f;

#pragma unroll
  for (int c = 0; c < 16; ++c) {
    const int cur = c & 1, nxt = cur ^ 1;
    SBAR();
    if (c < 15) {   // next c-iter's K + rel loads
      int kn = wk + (c + 1) * 16;
      const unsigned short* kr = kbase + (size_t)kn * N3;
      k0s[nxt] = *(const short8*)(kr + lhi * 8);
      k1s[nxt] = *(const short8*)(kr + 32 + lhi * 8);
      Ra[nxt] = *(const float4*)(relrow + kn + lhi * 4);
      Rb[nxt] = *(const float4*)(rel2row + kn + lhi * 4);
    }
    if ((c & 1) == 0) {   // V-frags for this 32-key window (used at end of odd c)
      int kb2 = wk + (c >> 1) * 32 + lhi * 8;
#pragma unroll
      for (int n = 0; n < 4; ++n)
        vf[n] = *(const short8*)(vtb + (size_t)(n * 16 + l15) * NS + kb2);
    }
    SBAR();
    // QK^T for current 16 keys
    f32x4 s = {};
    s = __builtin_amdgcn_mfma_f32_16x16x32_bf16(k0s[cur], qa0, s, 0, 0, 0);
    s = __builtin_amdgcn_mfma_f32_16x16x32_bf16(k1s[cur], qa1, s, 0, 0, 0);
    int mb = (int)((mw[c >> 2] >> ((c & 3) * 16 + lhi * 4)) & 0xFull);
    float p0 = (mb & 1) ? 0.f : __expf(s[0] + Ra[cur].x + Rb[cur].x);
    float p1 = (mb & 2) ? 0.f : __expf(s[1] + Ra[cur].y + Rb[cur].y);
    float p2 = (mb & 4) ? 0.f : __expf(s[2] + Ra[cur].z + Rb[cur].z);
    float p3 = (mb & 8) ? 0.f : __expf(s[3] + Ra[cur].w + Rb[cur].w);
    rs += (p0 + p1) + (p2 + p3);
    ushort4 pw;
    pw.x = f2bf(p0); pw.y = f2bf(p1); pw.z = f2bf(p2); pw.w = f2bf(p3);
    pk[c][0] = (unsigned int)pw.x | ((unsigned int)pw.y << 16);
    pk[c][1] = (unsigned int)pw.z | ((unsigned int)pw.w << 16);
    // stage this 16-key strip: row l15, cols (c&1)*16 + lhi*4 .. +3
    *(ushort4*)(&stage[w][l15][(c & 1) * 16 + lhi * 4]) = pw;
    if (c & 1) {
      // window complete: A-frag = stage[l15][lhi*8..+7]  (keys wk + (c>>1)*32 + lhi*8)
      short8 pa = *(const short8*)(&stage[w][l15][lhi * 8]);
#pragma unroll
      for (int n = 0; n < 4; ++n)
        cacc[n] = __builtin_amdgcn_mfma_f32_16x16x32_bf16(pa, vf[n], cacc[n], 0, 0, 0);
    }
    SBAR();
  }

  // row sums: reduce lhi-groups within wave, then across 4 waves
  rs += __shfl_xor(rs, 16);
  rs += __shfl_xor(rs, 32);
  if (lhi == 0) rs_lds[w][l15] = rs;
  __syncthreads();
  if (t < 16)
    inv_lds[t] = 1.0f / (rs_lds[0][t] + rs_lds[1][t] + rs_lds[2][t] + rs_lds[3][t]);
  __syncthreads();

  // probs out from pk registers: row = qt*16 + l15, cols wk + c*16 + lhi*4
  {
    float* probs = outp + (size_t)NB * NS * NHID;
    float inv = inv_lds[l15];
    size_t base = ((size_t)bh * NS + qt * 16 + l15) * NS + wk + lhi * 4;
#pragma unroll
    for (int c = 0; c < 16; ++c) {
      unsigned int u0 = pk[c][0], u1 = pk[c][1];
      float4 o;
      o.x = __uint_as_float(u0 << 16) * inv;
      o.y = __uint_as_float(u0 & 0xFFFF0000u) * inv;
      o.z = __uint_as_float(u1 << 16) * inv;
      o.w = __uint_as_float(u1 & 0xFFFF0000u) * inv;
      *(float4*)(&probs[base + c * 16]) = o;
    }
  }

  // ctx: cross-wave reduce via ctx_lds
#pragma unroll
  for (int n = 0; n < 4; ++n)
#pragma unroll
    for (int r = 0; r < 4; ++r)
      ctx_lds[w][lhi * 4 + r][n * 16 + l15] = cacc[n][r];
  __syncthreads();
#pragma unroll
  for (int i = 0; i < 4; ++i) {
    int idx = t + 256 * i;
    int q = idx >> 6, d = idx & 63;
    float s = ctx_lds[0][q][d] + ctx_lds[1][q][d] + ctx_lds[2][q][d] + ctx_lds[3][q][d];
    outp[(size_t)(b * NS + qt * 16 + q) * NHID + h * ND + d] = s * inv_lds[q];
  }
}

extern "C" void kernel_launch(void* const* d_in, const int* in_sizes, int n_in,
                              void* d_out, int out_size, void* d_ws, size_t ws_size,
                              hipStream_t stream) {
  const float* hidden = (const float*)d_in[0];
  const int* mask = (const int*)d_in[1];
  const float* relp = (const float*)d_in[2];
  const float* rel2 = (const float*)d_in[3];
  const float* Wq = (const float*)d_in[4];
  const float* qb = (const float*)d_in[5];
  const float* vb = (const float*)d_in[6];
  float* out = (float*)d_out;

  const size_t OFF_AHS = 0;                       // 8192*768*2
  const size_t OFF_WT  = 12582912;                // 2304*768*2
  const size_t OFF_QKV = 16121856;                // 8192*2304*2
  const size_t OFF_VT  = 53870592;                // 96*64*1024*2
  const size_t OFF_MB  = 66453504;                // 8*16*8 = 1024
  if (ws_size < 66454528) return;

  char* ws = (char*)d_ws;
  unsigned short* Ahs  = (unsigned short*)(ws + OFF_AHS);
  unsigned short* Wt   = (unsigned short*)(ws + OFF_WT);
  unsigned short* qkvb = (unsigned short*)(ws + OFF_QKV);
  unsigned short* Vt   = (unsigned short*)(ws + OFF_VT);
  unsigned long long* mb = (unsigned long long*)(ws + OFF_MB);

  k_cast<<<dim3(6144), dim3(256), 0, stream>>>(hidden, Ahs, (NB * NS * NHID) / 4);
  k_mask<<<dim3(8), dim3(1024), 0, stream>>>(mask, mb);
  k_wt<<<dim3(24, 72), dim3(256), 0, stream>>>(Wq, Wt);
  k_qkv<<<dim3(64, 36), dim3(256), 0, stream>>>(Ahs, Wt, qb, vb, qkvb);
  k_vt<<<dim3(32, 2, 96), dim3(256), 0, stream>>>(qkvb, Vt);
  k_attn<<<dim3(64, 12, 8), dim3(256), 0, stream>>>(qkvb, Vt, relp, rel2, mb, out);
}

// Round 8
// 519.126 us; speedup vs baseline: 1.1093x; 1.1093x over previous
//
#include <hip/hip_runtime.h>
#include <hip/hip_bf16.h>

typedef __attribute__((ext_vector_type(8))) short short8;
typedef __attribute__((ext_vector_type(4))) float f32x4;

#define NB 8
#define NS 1024
#define NH 12
#define ND 64
#define NHID 768
#define N3 2304

#define SBAR() __builtin_amdgcn_sched_barrier(0)

__device__ __forceinline__ unsigned short f2bf(float f) {
  __hip_bfloat16 h = __float2bfloat16(f);
  return *reinterpret_cast<unsigned short*>(&h);
}
__device__ __forceinline__ float bf2f(unsigned short u) {
  __hip_bfloat16 h;
  *reinterpret_cast<unsigned short*>(&h) = u;
  return __bfloat162float(h);
}

// ---- cast hidden f32 -> bf16 ----
__global__ void k_cast(const float* __restrict__ in, unsigned short* __restrict__ out, int n4) {
  int i = blockIdx.x * blockDim.x + threadIdx.x;
  if (i >= n4) return;
  float4 v = ((const float4*)in)[i];
  ushort4 o;
  o.x = f2bf(v.x); o.y = f2bf(v.y); o.z = f2bf(v.z); o.w = f2bf(v.w);
  ((ushort4*)out)[i] = o;
}

// ---- pack mask [B][S] int -> bitmask [B][16] u64 ----
__global__ void k_mask(const int* __restrict__ mask, unsigned long long* __restrict__ bits) {
  int b = blockIdx.x, t = threadIdx.x;
  unsigned long long bal = __ballot(mask[b * NS + t] != 0);
  if ((t & 63) == 0) bits[b * 16 + (t >> 6)] = bal;
}

// ---- transpose-cast W [768][2304] f32 -> Wt [2304][768] bf16 ----
__global__ __launch_bounds__(256) void k_wt(const float* __restrict__ W, unsigned short* __restrict__ Wt) {
  __shared__ float tile[32][33];
  int r0 = blockIdx.x * 32;   // over 768
  int c0 = blockIdx.y * 32;   // over 2304
  int tx = threadIdx.x & 31, ty = threadIdx.x >> 5;
#pragma unroll
  for (int p = 0; p < 4; ++p)
    tile[ty + 8*p][tx] = W[(size_t)(r0 + ty + 8*p) * N3 + c0 + tx];
  __syncthreads();
#pragma unroll
  for (int p = 0; p < 4; ++p)
    Wt[(size_t)(c0 + ty + 8*p) * NHID + r0 + tx] = f2bf(tile[tx][ty + 8*p]);
}

// ---- QKV GEMM: [8192][768]bf16 @ Wt[2304][768]bf16 -> qkv [8192][2304]bf16 ----
__global__ __launch_bounds__(256) void k_qkv(const unsigned short* __restrict__ A,
                                             const unsigned short* __restrict__ Wt,
                                             const float* __restrict__ qb,
                                             const float* __restrict__ vb,
                                             unsigned short* __restrict__ out) {
  const int t = threadIdx.x;
  const int w = t >> 6, l = t & 63, l15 = l & 15, lhi = l >> 4;
  const int rowbase = blockIdx.x * 128 + w * 32;
  const int colbase = blockIdx.y * 64;

  f32x4 acc[2][4] = {};
  const unsigned short* arow0 = A + (size_t)(rowbase + l15) * NHID;
  const unsigned short* arow1 = A + (size_t)(rowbase + 16 + l15) * NHID;
  const unsigned short* wrows[4];
#pragma unroll
  for (int n = 0; n < 4; ++n)
    wrows[n] = Wt + (size_t)(colbase + n * 16 + l15) * NHID;

  for (int k0 = 0; k0 < NHID; k0 += 32) {
    short8 a0 = *(const short8*)(arow0 + k0 + lhi * 8);
    short8 a1 = *(const short8*)(arow1 + k0 + lhi * 8);
#pragma unroll
    for (int n = 0; n < 4; ++n) {
      short8 bfr = *(const short8*)(wrows[n] + k0 + lhi * 8);
      acc[0][n] = __builtin_amdgcn_mfma_f32_16x16x32_bf16(a0, bfr, acc[0][n], 0, 0, 0);
      acc[1][n] = __builtin_amdgcn_mfma_f32_16x16x32_bf16(a1, bfr, acc[1][n], 0, 0, 0);
    }
  }
  const int seg = colbase / NHID;   // uniform per block: 0=q 1=k 2=v
#pragma unroll
  for (int n = 0; n < 4; ++n) {
    int col = colbase + n * 16 + l15;
    int cc = col % NHID;
    float bias = (seg == 0) ? qb[cc] : (seg == 2) ? vb[cc] : 0.0f;
#pragma unroll
    for (int m = 0; m < 2; ++m) {
#pragma unroll
      for (int r = 0; r < 4; ++r) {
        int row = rowbase + m * 16 + lhi * 4 + r;
        float v = acc[m][n][r];
        if (seg == 0) v = (v + bias) * 0.125f;
        else if (seg == 2) v = v + bias;
        out[(size_t)row * N3 + col] = f2bf(v);
      }
    }
  }
}

// ---- transpose V (cols 1536..2303 of qkv) -> Vt [96][64][1024] bf16 ----
__global__ __launch_bounds__(256) void k_vt(const unsigned short* __restrict__ qkvb,
                                            unsigned short* __restrict__ Vt) {
  __shared__ unsigned short tile[32][33];
  int s0 = blockIdx.x * 32;  // over 1024
  int d0 = blockIdx.y * 32;  // over 64
  int bh = blockIdx.z;       // 0..95
  int b = bh / NH;
  int hcol = (bh % NH) * ND;
  int tx = threadIdx.x & 31, ty = threadIdx.x >> 5;
#pragma unroll
  for (int p = 0; p < 4; ++p) {
    int s = s0 + ty + 8*p;
    tile[ty + 8*p][tx] = qkvb[(size_t)(b * NS + s) * N3 + 2 * NHID + hcol + d0 + tx];
  }
  __syncthreads();
#pragma unroll
  for (int p = 0; p < 4; ++p) {
    int d = d0 + ty + 8*p;
    Vt[((size_t)bh * ND + d) * NS + s0 + tx] = tile[tx][ty + 8*p];
  }
}

// ---- fused attention: one block per (qtile16, h, b), 4 waves x 256 keys ----
// rel+rel2 staged through LDS with CONTIGUOUS 1-KB row-run loads (DRAM page
// locality), pre-summed + bf16-packed into swizzled relsum[16][128] per wave,
// double-buffered across two 128-key chunks. K uses rolling 1-ahead prefetch.
// p_lds swizzle col ^ (l15<<2); reused as f32 ctx partials [4][16][64].
__global__ __launch_bounds__(256, 2) void k_attn(const unsigned short* __restrict__ qkvb,
                                                 const unsigned short* __restrict__ Vt,
                                                 const float* __restrict__ relp,
                                                 const float* __restrict__ rel2,
                                                 const unsigned long long* __restrict__ mbits,
                                                 float* __restrict__ outp) {
  __shared__ __align__(16) unsigned short p_lds[16][1024];       // 32 KB; reused as f32[4][16][64]
  __shared__ __align__(16) unsigned short relsum[4][2][16][128]; // 32 KB staged rel+rel2 (bf16)
  __shared__ float rs_lds[4][16];
  __shared__ float inv_lds[16];

  const int qt = blockIdx.x, h = blockIdx.y, b = blockIdx.z;
  const int t = threadIdx.x, w = t >> 6, l = t & 63, l15 = l & 15, lhi = l >> 4;
  const int bh = b * NH + h;
  const int swz = l15 << 2;
  const int wk = w * 256;                       // this wave's key base
  const int srow = (l >> 5);                    // stage: row within pair
  const int scol = (l & 31) * 4;                // stage: col (floats)

  // Q fragments (16 rows x 64 d); q already scaled+biased in k_qkv
  const unsigned short* qrowp = qkvb + (size_t)(b * NS + qt * 16 + l15) * N3 + h * ND;
  short8 qa0 = *(const short8*)(qrowp + lhi * 8);
  short8 qa1 = *(const short8*)(qrowp + 32 + lhi * 8);

  const float* relq  = relp + ((size_t)bh * NS + qt * 16) * NS;
  const float* rel2q = rel2 + ((size_t)bh * NS + qt * 16) * NS;
  const unsigned long long* mwp = mbits + b * 16 + w * 4;
  unsigned long long mw[4];
#pragma unroll
  for (int i = 0; i < 4; ++i) mw[i] = mwp[i];

  const unsigned short* kbase = qkvb + (size_t)(b * NS + l15) * N3 + NHID + h * ND;

  // ---- stage chunk 0 (keys wk..wk+127): contiguous 1-KB row-run loads ----
  float4 SR[8], S2[8];
#pragma unroll
  for (int j = 0; j < 8; ++j) {
    int row = j * 2 + srow;
    SR[j] = *(const float4*)(relq  + (size_t)row * NS + wk + scol);
    S2[j] = *(const float4*)(rel2q + (size_t)row * NS + wk + scol);
  }
  SBAR();
  // K for c=0 (issued after stage loads; convert's vmcnt wait keeps these in flight)
  short8 k0s[2], k1s[2];
  {
    const unsigned short* kr = kbase + (size_t)wk * N3;
    k0s[0] = *(const short8*)(kr + lhi * 8);
    k1s[0] = *(const short8*)(kr + 32 + lhi * 8);
  }
  SBAR();
  // convert + write buf0 (sum, bf16, swizzled: col ^ ((row&15)<<3) in shorts)
#pragma unroll
  for (int j = 0; j < 8; ++j) {
    int row = j * 2 + srow;
    ushort4 u;
    u.x = f2bf(SR[j].x + S2[j].x);
    u.y = f2bf(SR[j].y + S2[j].y);
    u.z = f2bf(SR[j].z + S2[j].z);
    u.w = f2bf(SR[j].w + S2[j].w);
    *(ushort4*)(&relsum[w][0][row][scol ^ (row << 3)]) = u;
  }

  float rs = 0.f;
#pragma unroll
  for (int c = 0; c < 16; ++c) {
    const int cur = c & 1, nxt = cur ^ 1;
    SBAR();
    if (c < 15) {   // rolling K prefetch (1 ahead)
      int kn = wk + (c + 1) * 16;
      const unsigned short* kr = kbase + (size_t)kn * N3;
      k0s[nxt] = *(const short8*)(kr + lhi * 8);
      k1s[nxt] = *(const short8*)(kr + 32 + lhi * 8);
    }
    if (c < 4) {    // stage chunk 1 loads, 4/iter (rowpairs 2c, 2c+1)
#pragma unroll
      for (int jj = 0; jj < 2; ++jj) {
        int j = c * 2 + jj;
        int row = j * 2 + srow;
        SR[j] = *(const float4*)(relq  + (size_t)row * NS + wk + 128 + scol);
        S2[j] = *(const float4*)(rel2q + (size_t)row * NS + wk + 128 + scol);
      }
    }
    SBAR();
    if (c == 8) {   // convert + write buf1 (loads done ~5 iters ago)
#pragma unroll
      for (int j = 0; j < 8; ++j) {
        int row = j * 2 + srow;
        ushort4 u;
        u.x = f2bf(SR[j].x + S2[j].x);
        u.y = f2bf(SR[j].y + S2[j].y);
        u.z = f2bf(SR[j].z + S2[j].z);
        u.w = f2bf(SR[j].w + S2[j].w);
        *(ushort4*)(&relsum[w][1][row][scol ^ (row << 3)]) = u;
      }
    }
    // consume: QK^T MFMA + relsum from LDS + exp + pack
    f32x4 s = {};
    s = __builtin_amdgcn_mfma_f32_16x16x32_bf16(k0s[cur], qa0, s, 0, 0, 0);
    s = __builtin_amdgcn_mfma_f32_16x16x32_bf16(k1s[cur], qa1, s, 0, 0, 0);
    ushort4 rsu = *(const ushort4*)(&relsum[w][c >> 3][l15][(((c & 7) * 16) + lhi * 4) ^ (l15 << 3)]);
    int mb = (int)((mw[c >> 2] >> ((c & 3) * 16 + lhi * 4)) & 0xFull);
    float p0 = (mb & 1) ? 0.f : __expf(s[0] + bf2f(rsu.x));
    float p1 = (mb & 2) ? 0.f : __expf(s[1] + bf2f(rsu.y));
    float p2 = (mb & 4) ? 0.f : __expf(s[2] + bf2f(rsu.z));
    float p3 = (mb & 8) ? 0.f : __expf(s[3] + bf2f(rsu.w));
    rs += (p0 + p1) + (p2 + p3);
    ushort4 pw;
    pw.x = f2bf(p0); pw.y = f2bf(p1); pw.z = f2bf(p2); pw.w = f2bf(p3);
    int kc = wk + c * 16 + lhi * 4;
    *(ushort4*)(&p_lds[l15][kc ^ swz]) = pw;
    SBAR();
  }

  // row sums: reduce lhi-groups within wave, then across 4 waves
  rs += __shfl_xor(rs, 16);
  rs += __shfl_xor(rs, 32);
  if (lhi == 0) rs_lds[w][l15] = rs;
  __syncthreads();
  if (t < 16)
    inv_lds[t] = 1.0f / (rs_lds[0][t] + rs_lds[1][t] + rs_lds[2][t] + rs_lds[3][t]);
  __syncthreads();

  // probs out (stores overlap the PV MFMAs that follow): wave w rows 4w..4w+3
  {
    float* probs = outp + (size_t)NB * NS * NHID;
#pragma unroll
    for (int rr = 0; rr < 4; ++rr) {
      int row = w * 4 + rr;
      float inv = inv_lds[row];
      int sz = row << 2;
      size_t base = ((size_t)bh * NS + qt * 16 + row) * NS;
#pragma unroll
      for (int i = 0; i < 4; ++i) {
        int col = 4 * l + 256 * i;
        ushort4 pv = *(const ushort4*)(&p_lds[row][col ^ sz]);
        float4 o;
        o.x = bf2f(pv.x) * inv;
        o.y = bf2f(pv.y) * inv;
        o.z = bf2f(pv.z) * inv;
        o.w = bf2f(pv.w) * inv;
        *(float4*)(&probs[base + col]) = o;
      }
    }
  }

  // phase 2: PV over own 256 keys, all 16 q-rows x 64 d (partials in regs)
  f32x4 cacc[4] = {};
  const unsigned short* vtb = Vt + (size_t)bh * ND * NS;
#pragma unroll
  for (int c2 = 0; c2 < 8; ++c2) {
    int kb2 = wk + c2 * 32 + lhi * 8;
    ushort4 pa0 = *(const ushort4*)(&p_lds[l15][kb2 ^ swz]);
    ushort4 pa1 = *(const ushort4*)(&p_lds[l15][(kb2 + 4) ^ swz]);
    short8 pa;
    pa[0] = pa0.x; pa[1] = pa0.y; pa[2] = pa0.z; pa[3] = pa0.w;
    pa[4] = pa1.x; pa[5] = pa1.y; pa[6] = pa1.z; pa[7] = pa1.w;
#pragma unroll
    for (int n = 0; n < 4; ++n) {
      short8 vf = *(const short8*)(vtb + (size_t)(n * 16 + l15) * NS + kb2);
      cacc[n] = __builtin_amdgcn_mfma_f32_16x16x32_bf16(pa, vf, cacc[n], 0, 0, 0);
    }
  }

  // all P reads done -> reuse p_lds as f32 ctx partials [4][16][64]
  __syncthreads();
  float* cpart = (float*)p_lds;
#pragma unroll
  for (int n = 0; n < 4; ++n)
#pragma unroll
    for (int r = 0; r < 4; ++r)
      cpart[w * 1024 + (lhi * 4 + r) * 64 + n * 16 + l15] = cacc[n][r];
  __syncthreads();

  // reduce 4 partials, scale, store ctx [B,S,HID]
#pragma unroll
  for (int i = 0; i < 4; ++i) {
    int idx = t + 256 * i;
    int q = idx >> 6, d = idx & 63;
    float s = cpart[idx] + cpart[1024 + idx] + cpart[2048 + idx] + cpart[3072 + idx];
    outp[(size_t)(b * NS + qt * 16 + q) * NHID + h * ND + d] = s * inv_lds[q];
  }
}

extern "C" void kernel_launch(void* const* d_in, const int* in_sizes, int n_in,
                              void* d_out, int out_size, void* d_ws, size_t ws_size,
                              hipStream_t stream) {
  const float* hidden = (const float*)d_in[0];
  const int* mask = (const int*)d_in[1];
  const float* relp = (const float*)d_in[2];
  const float* rel2 = (const float*)d_in[3];
  const float* Wq = (const float*)d_in[4];
  const float* qb = (const float*)d_in[5];
  const float* vb = (const float*)d_in[6];
  float* out = (float*)d_out;

  const size_t OFF_AHS = 0;                       // 8192*768*2
  const size_t OFF_WT  = 12582912;                // 2304*768*2
  const size_t OFF_QKV = 16121856;                // 8192*2304*2
  const size_t OFF_VT  = 53870592;                // 96*64*1024*2
  const size_t OFF_MB  = 66453504;                // 8*16*8 = 1024
  if (ws_size < 66454528) return;

  char* ws = (char*)d_ws;
  unsigned short* Ahs  = (unsigned short*)(ws + OFF_AHS);
  unsigned short* Wt   = (unsigned short*)(ws + OFF_WT);
  unsigned short* qkvb = (unsigned short*)(ws + OFF_QKV);
  unsigned short* Vt   = (unsigned short*)(ws + OFF_VT);
  unsigned long long* mb = (unsigned long long*)(ws + OFF_MB);

  k_cast<<<dim3(6144), dim3(256), 0, stream>>>(hidden, Ahs, (NB * NS * NHID) / 4);
  k_mask<<<dim3(8), dim3(1024), 0, stream>>>(mask, mb);
  k_wt<<<dim3(24, 72), dim3(256), 0, stream>>>(Wq, Wt);
  k_qkv<<<dim3(64, 36), dim3(256), 0, stream>>>(Ahs, Wt, qb, vb, qkvb);
  k_vt<<<dim3(32, 2, 96), dim3(256), 0, stream>>>(qkvb, Vt);
  k_attn<<<dim3(64, 12, 8), dim3(256), 0, stream>>>(qkvb, Vt, relp, rel2, mb, out);
}

// Round 9
// 488.598 us; speedup vs baseline: 1.1787x; 1.0625x over previous
//
#include <hip/hip_runtime.h>
#include <hip/hip_bf16.h>

typedef __attribute__((ext_vector_type(8))) short short8;
typedef __attribute__((ext_vector_type(4))) float f32x4;

#define NB 8
#define NS 1024
#define NH 12
#define ND 64
#define NHID 768
#define N3 2304

#define SBAR() __builtin_amdgcn_sched_barrier(0)

__device__ __forceinline__ unsigned short f2bf(float f) {
  __hip_bfloat16 h = __float2bfloat16(f);
  return *reinterpret_cast<unsigned short*>(&h);
}
__device__ __forceinline__ float bf2f(unsigned short u) {
  __hip_bfloat16 h;
  *reinterpret_cast<unsigned short*>(&h) = u;
  return __bfloat162float(h);
}

// ---- cast hidden f32 -> bf16 ----
__global__ void k_cast(const float* __restrict__ in, unsigned short* __restrict__ out, int n4) {
  int i = blockIdx.x * blockDim.x + threadIdx.x;
  if (i >= n4) return;
  float4 v = ((const float4*)in)[i];
  ushort4 o;
  o.x = f2bf(v.x); o.y = f2bf(v.y); o.z = f2bf(v.z); o.w = f2bf(v.w);
  ((ushort4*)out)[i] = o;
}

// ---- pack mask [B][S] int -> bitmask [B][16] u64 ----
__global__ void k_mask(const int* __restrict__ mask, unsigned long long* __restrict__ bits) {
  int b = blockIdx.x, t = threadIdx.x;
  unsigned long long bal = __ballot(mask[b * NS + t] != 0);
  if ((t & 63) == 0) bits[b * 16 + (t >> 6)] = bal;
}

// ---- transpose-cast W [768][2304] f32 -> Wt [2304][768] bf16 ----
__global__ __launch_bounds__(256) void k_wt(const float* __restrict__ W, unsigned short* __restrict__ Wt) {
  __shared__ float tile[32][33];
  int r0 = blockIdx.x * 32;   // over 768
  int c0 = blockIdx.y * 32;   // over 2304
  int tx = threadIdx.x & 31, ty = threadIdx.x >> 5;
#pragma unroll
  for (int p = 0; p < 4; ++p)
    tile[ty + 8*p][tx] = W[(size_t)(r0 + ty + 8*p) * N3 + c0 + tx];
  __syncthreads();
#pragma unroll
  for (int p = 0; p < 4; ++p)
    Wt[(size_t)(c0 + ty + 8*p) * NHID + r0 + tx] = f2bf(tile[tx][ty + 8*p]);
}

// ---- QKV GEMM: [8192][768]bf16 @ Wt[2304][768]bf16 -> qkv [8192][2304]bf16 ----
__global__ __launch_bounds__(256) void k_qkv(const unsigned short* __restrict__ A,
                                             const unsigned short* __restrict__ Wt,
                                             const float* __restrict__ qb,
                                             const float* __restrict__ vb,
                                             unsigned short* __restrict__ out) {
  const int t = threadIdx.x;
  const int w = t >> 6, l = t & 63, l15 = l & 15, lhi = l >> 4;
  const int rowbase = blockIdx.x * 128 + w * 32;
  const int colbase = blockIdx.y * 64;

  f32x4 acc[2][4] = {};
  const unsigned short* arow0 = A + (size_t)(rowbase + l15) * NHID;
  const unsigned short* arow1 = A + (size_t)(rowbase + 16 + l15) * NHID;
  const unsigned short* wrows[4];
#pragma unroll
  for (int n = 0; n < 4; ++n)
    wrows[n] = Wt + (size_t)(colbase + n * 16 + l15) * NHID;

  for (int k0 = 0; k0 < NHID; k0 += 32) {
    short8 a0 = *(const short8*)(arow0 + k0 + lhi * 8);
    short8 a1 = *(const short8*)(arow1 + k0 + lhi * 8);
#pragma unroll
    for (int n = 0; n < 4; ++n) {
      short8 bfr = *(const short8*)(wrows[n] + k0 + lhi * 8);
      acc[0][n] = __builtin_amdgcn_mfma_f32_16x16x32_bf16(a0, bfr, acc[0][n], 0, 0, 0);
      acc[1][n] = __builtin_amdgcn_mfma_f32_16x16x32_bf16(a1, bfr, acc[1][n], 0, 0, 0);
    }
  }
  const int seg = colbase / NHID;   // uniform per block: 0=q 1=k 2=v
#pragma unroll
  for (int n = 0; n < 4; ++n) {
    int col = colbase + n * 16 + l15;
    int cc = col % NHID;
    float bias = (seg == 0) ? qb[cc] : (seg == 2) ? vb[cc] : 0.0f;
#pragma unroll
    for (int m = 0; m < 2; ++m) {
#pragma unroll
      for (int r = 0; r < 4; ++r) {
        int row = rowbase + m * 16 + lhi * 4 + r;
        float v = acc[m][n][r];
        if (seg == 0) v = (v + bias) * 0.125f;
        else if (seg == 2) v = v + bias;
        out[(size_t)row * N3 + col] = f2bf(v);
      }
    }
  }
}

// ---- transpose V (cols 1536..2303 of qkv) -> Vt [96][64][1024] bf16 ----
__global__ __launch_bounds__(256) void k_vt(const unsigned short* __restrict__ qkvb,
                                            unsigned short* __restrict__ Vt) {
  __shared__ unsigned short tile[32][33];
  int s0 = blockIdx.x * 32;  // over 1024
  int d0 = blockIdx.y * 32;  // over 64
  int bh = blockIdx.z;       // 0..95
  int b = bh / NH;
  int hcol = (bh % NH) * ND;
  int tx = threadIdx.x & 31, ty = threadIdx.x >> 5;
#pragma unroll
  for (int p = 0; p < 4; ++p) {
    int s = s0 + ty + 8*p;
    tile[ty + 8*p][tx] = qkvb[(size_t)(b * NS + s) * N3 + 2 * NHID + hcol + d0 + tx];
  }
  __syncthreads();
#pragma unroll
  for (int p = 0; p < 4; ++p) {
    int d = d0 + ty + 8*p;
    Vt[((size_t)bh * ND + d) * NS + s0 + tx] = tile[tx][ty + 8*p];
  }
}

// ---- fused attention, chunk-staged streaming pipeline ----
// Block (qt,h,b): 16 q-rows x 1024 keys, 4 waves. 8 chunks of 128 keys.
// Per chunk: reg-stage K(16K)+V(16K)+relsum(4K,bf16 presummed) into
// XOR-swizzled LDS (double-buffered); iteration = {ds_write c; issue loads
// c+1; barrier; consume c (QK MFMA + exp + PV MFMA, all from LDS)}.
// P kept packed in 32 VGPRs for the probs write. 1 barrier/chunk.
__global__ __launch_bounds__(256, 2) void k_attn(const unsigned short* __restrict__ qkvb,
                                                 const unsigned short* __restrict__ Vt,
                                                 const float* __restrict__ relp,
                                                 const float* __restrict__ rel2,
                                                 const unsigned long long* __restrict__ mbits,
                                                 float* __restrict__ outp) {
  __shared__ __align__(16) char Ks[2][16384];           // [128 key][64 d] bf16, swz
  __shared__ __align__(16) char Vs[2][16384];           // [64 d][128 key] bf16, swz
  __shared__ __align__(16) char Rs[2][4096];            // [16 q][128 key] bf16 relsum, swz
  __shared__ __align__(16) unsigned short stg[4][16][40]; // per-wave P window
  __shared__ float rs_lds[4][16];
  __shared__ float inv_lds[16];

  const int qt = blockIdx.x, h = blockIdx.y, b = blockIdx.z;
  const int t = threadIdx.x, w = t >> 6, l = t & 63, l15 = l & 15, lhi = l >> 4;
  const int bh = b * NH + h;

  // staging thread->data mapping (block-wide, per chunk)
  const int skk = t >> 1;            // K key-row 0..127
  const int skc = (t & 1) * 64;      // K byte-col base (+i*16, i<4)
  const int svd = t >> 2;            // V d-row 0..63
  const int svc = (t & 3) * 64;      // V byte-col base (+i*16, i<4)
  const int srr = t >> 4;            // rel q-row 0..15
  const int src = (t & 15) * 8;      // rel f32-col base (+i*4, i<2)
  const int kwz = (skk & 7) << 4, vwz = (svd & 7) << 4, rwz = (srr & 7) << 4;

  // Q fragments (q already scaled+biased in k_qkv)
  const unsigned short* qrowp = qkvb + (size_t)(b * NS + qt * 16 + l15) * N3 + h * ND;
  short8 qa0 = *(const short8*)(qrowp + lhi * 8);
  short8 qa1 = *(const short8*)(qrowp + 32 + lhi * 8);

  unsigned long long mw[8];
#pragma unroll
  for (int c = 0; c < 8; ++c) mw[c] = mbits[b * 16 + c * 2 + (w >> 1)];

  const unsigned short* kgbase = qkvb + (size_t)(b * NS + skk) * N3 + NHID + h * ND + (skc >> 1);
  const unsigned short* vgbase = Vt + (size_t)(bh * ND + svd) * NS + (svc >> 1);
  const float* rgbase  = relp + ((size_t)(bh * NS + qt * 16 + srr)) * NS + src;
  const float* r2gbase = rel2 + ((size_t)(bh * NS + qt * 16 + srr)) * NS + src;

  short8 kr0, kr1, kr2, kr3, vr0, vr1, vr2, vr3;
  float4 ra0, ra1, rb0, rb1;

#define STAGE_LOAD(c) do {                                              \
    const unsigned short* kg = kgbase + (size_t)(c) * 128 * N3;         \
    kr0 = *(const short8*)(kg);      kr1 = *(const short8*)(kg + 8);    \
    kr2 = *(const short8*)(kg + 16); kr3 = *(const short8*)(kg + 24);   \
    const unsigned short* vg = vgbase + (c) * 128;                      \
    vr0 = *(const short8*)(vg);      vr1 = *(const short8*)(vg + 8);    \
    vr2 = *(const short8*)(vg + 16); vr3 = *(const short8*)(vg + 24);   \
    const float* rg = rgbase + (c) * 128;                               \
    ra0 = *(const float4*)(rg);  ra1 = *(const float4*)(rg + 4);        \
    const float* r2g = r2gbase + (c) * 128;                             \
    rb0 = *(const float4*)(r2g); rb1 = *(const float4*)(r2g + 4);       \
  } while (0)

#define STAGE_WRITE(buf) do {                                           \
    char* KB = Ks[buf];                                                 \
    *(short8*)(KB + skk * 128 + ((skc +  0) ^ kwz)) = kr0;              \
    *(short8*)(KB + skk * 128 + ((skc + 16) ^ kwz)) = kr1;              \
    *(short8*)(KB + skk * 128 + ((skc + 32) ^ kwz)) = kr2;              \
    *(short8*)(KB + skk * 128 + ((skc + 48) ^ kwz)) = kr3;              \
    char* VB = Vs[buf];                                                 \
    *(short8*)(VB + svd * 256 + ((svc +  0) ^ vwz)) = vr0;              \
    *(short8*)(VB + svd * 256 + ((svc + 16) ^ vwz)) = vr1;              \
    *(short8*)(VB + svd * 256 + ((svc + 32) ^ vwz)) = vr2;              \
    *(short8*)(VB + svd * 256 + ((svc + 48) ^ vwz)) = vr3;              \
    char* RB = Rs[buf];                                                 \
    ushort4 u0, u1;                                                     \
    u0.x = f2bf(ra0.x + rb0.x); u0.y = f2bf(ra0.y + rb0.y);             \
    u0.z = f2bf(ra0.z + rb0.z); u0.w = f2bf(ra0.w + rb0.w);             \
    u1.x = f2bf(ra1.x + rb1.x); u1.y = f2bf(ra1.y + rb1.y);             \
    u1.z = f2bf(ra1.z + rb1.z); u1.w = f2bf(ra1.w + rb1.w);             \
    *(ushort4*)(RB + srr * 256 + ((src * 2 + 0) ^ rwz)) = u0;           \
    *(ushort4*)(RB + srr * 256 + ((src * 2 + 8) ^ rwz)) = u1;           \
  } while (0)

  unsigned int pkA[8][2], pkB[8][2];
  f32x4 cacc[4] = {};
  float rs = 0.f;

  STAGE_LOAD(0);
#pragma unroll
  for (int c = 0; c < 8; ++c) {
    const int buf = c & 1;
    STAGE_WRITE(buf);              // waits chunk c's loads (issued last iter)
    SBAR();
    if (c < 7) STAGE_LOAD(c + 1);  // in flight across the whole consume
    SBAR();
    __syncthreads();               // chunk c visible to all waves

    // ---- consume chunk c ----
    const char* KB = Ks[buf]; const char* VB = Vs[buf]; const char* RB = Rs[buf];
#pragma unroll
    for (int s = 0; s < 2; ++s) {
      int kkr = w * 32 + s * 16 + l15;
      int kx = (kkr & 7) << 4;
      short8 kf0 = *(const short8*)(KB + kkr * 128 + ((lhi * 16) ^ kx));
      short8 kf1 = *(const short8*)(KB + kkr * 128 + ((64 + lhi * 16) ^ kx));
      f32x4 sc = {};
      sc = __builtin_amdgcn_mfma_f32_16x16x32_bf16(kf0, qa0, sc, 0, 0, 0);
      sc = __builtin_amdgcn_mfma_f32_16x16x32_bf16(kf1, qa1, sc, 0, 0, 0);
      ushort4 rsu = *(const ushort4*)(RB + l15 * 256 + ((w * 64 + s * 32 + lhi * 8) ^ ((l15 & 7) << 4)));
      int mb = (int)((mw[c] >> ((w & 1) * 32 + s * 16 + lhi * 4)) & 0xFull);
      float p0 = (mb & 1) ? 0.f : __expf(sc[0] + bf2f(rsu.x));
      float p1 = (mb & 2) ? 0.f : __expf(sc[1] + bf2f(rsu.y));
      float p2 = (mb & 4) ? 0.f : __expf(sc[2] + bf2f(rsu.z));
      float p3 = (mb & 8) ? 0.f : __expf(sc[3] + bf2f(rsu.w));
      rs += (p0 + p1) + (p2 + p3);
      ushort4 pw;
      pw.x = f2bf(p0); pw.y = f2bf(p1); pw.z = f2bf(p2); pw.w = f2bf(p3);
      pkA[c][s] = (unsigned int)pw.x | ((unsigned int)pw.y << 16);
      pkB[c][s] = (unsigned int)pw.z | ((unsigned int)pw.w << 16);
      *(ushort4*)(&stg[w][l15][s * 16 + lhi * 4]) = pw;
    }
    SBAR();                        // stage writes before pa read (HW is in-order)
    short8 pa = *(const short8*)(&stg[w][l15][lhi * 8]);
#pragma unroll
    for (int n = 0; n < 4; ++n) {
      int dr = n * 16 + l15;
      short8 vf = *(const short8*)(VB + dr * 256 + ((w * 64 + lhi * 16) ^ ((dr & 7) << 4)));
      cacc[n] = __builtin_amdgcn_mfma_f32_16x16x32_bf16(pa, vf, cacc[n], 0, 0, 0);
    }
  }

  // row sums -> inv
  rs += __shfl_xor(rs, 16);
  rs += __shfl_xor(rs, 32);
  if (lhi == 0) rs_lds[w][l15] = rs;
  __syncthreads();
  if (t < 16)
    inv_lds[t] = 1.0f / (rs_lds[0][t] + rs_lds[1][t] + rs_lds[2][t] + rs_lds[3][t]);
  __syncthreads();

  // probs out from pk regs: row = qt*16 + l15, col = c*128 + w*32 + s*16 + lhi*4
  {
    float* probs = outp + (size_t)NB * NS * NHID;
    float inv = inv_lds[l15];
    size_t prow = ((size_t)bh * NS + qt * 16 + l15) * NS;
#pragma unroll
    for (int c = 0; c < 8; ++c)
#pragma unroll
      for (int s = 0; s < 2; ++s) {
        int col = c * 128 + w * 32 + s * 16 + lhi * 4;
        unsigned int u0 = pkA[c][s], u1 = pkB[c][s];
        float4 o;
        o.x = __uint_as_float(u0 << 16) * inv;
        o.y = __uint_as_float(u0 & 0xFFFF0000u) * inv;
        o.z = __uint_as_float(u1 << 16) * inv;
        o.w = __uint_as_float(u1 & 0xFFFF0000u) * inv;
        *(float4*)(&probs[prow + col]) = o;
      }
  }

  // ctx: cross-wave reduce via reuse of Ks[0] (16 KB)
  float* cpart = (float*)Ks;
#pragma unroll
  for (int n = 0; n < 4; ++n)
#pragma unroll
    for (int r = 0; r < 4; ++r)
      cpart[w * 1024 + (lhi * 4 + r) * 64 + n * 16 + l15] = cacc[n][r];
  __syncthreads();
#pragma unroll
  for (int i = 0; i < 4; ++i) {
    int idx = t + 256 * i;
    int q = idx >> 6, d = idx & 63;
    float s = cpart[idx] + cpart[1024 + idx] + cpart[2048 + idx] + cpart[3072 + idx];
    outp[(size_t)(b * NS + qt * 16 + q) * NHID + h * ND + d] = s * inv_lds[q];
  }
#undef STAGE_LOAD
#undef STAGE_WRITE
}

extern "C" void kernel_launch(void* const* d_in, const int* in_sizes, int n_in,
                              void* d_out, int out_size, void* d_ws, size_t ws_size,
                              hipStream_t stream) {
  const float* hidden = (const float*)d_in[0];
  const int* mask = (const int*)d_in[1];
  const float* relp = (const float*)d_in[2];
  const float* rel2 = (const float*)d_in[3];
  const float* Wq = (const float*)d_in[4];
  const float* qb = (const float*)d_in[5];
  const float* vb = (const float*)d_in[6];
  float* out = (float*)d_out;

  const size_t OFF_AHS = 0;                       // 8192*768*2
  const size_t OFF_WT  = 12582912;                // 2304*768*2
  const size_t OFF_QKV = 16121856;                // 8192*2304*2
  const size_t OFF_VT  = 53870592;                // 96*64*1024*2
  const size_t OFF_MB  = 66453504;                // 8*16*8 = 1024
  if (ws_size < 66454528) return;

  char* ws = (char*)d_ws;
  unsigned short* Ahs  = (unsigned short*)(ws + OFF_AHS);
  unsigned short* Wt   = (unsigned short*)(ws + OFF_WT);
  unsigned short* qkvb = (unsigned short*)(ws + OFF_QKV);
  unsigned short* Vt   = (unsigned short*)(ws + OFF_VT);
  unsigned long long* mb = (unsigned long long*)(ws + OFF_MB);

  k_cast<<<dim3(6144), dim3(256), 0, stream>>>(hidden, Ahs, (NB * NS * NHID) / 4);
  k_mask<<<dim3(8), dim3(1024), 0, stream>>>(mask, mb);
  k_wt<<<dim3(24, 72), dim3(256), 0, stream>>>(Wq, Wt);
  k_qkv<<<dim3(64, 36), dim3(256), 0, stream>>>(Ahs, Wt, qb, vb, qkvb);
  k_vt<<<dim3(32, 2, 96), dim3(256), 0, stream>>>(qkvb, Vt);
  k_attn<<<dim3(64, 12, 8), dim3(256), 0, stream>>>(qkvb, Vt, relp, rel2, mb, out);
}